// Round 10
// baseline (60.444 us; speedup 1.0000x reference)
//
#include <hip/hip_runtime.h>
#include <hip/hip_bf16.h>
#include <stdint.h>

// Problem constants: B=8, T=2048, C=1024, H=64. Single-head causal attention.
#define Bn 8
#define Tn 2048
#define Cn 1024
#define Hn 64

typedef __attribute__((ext_vector_type(8))) short bf16x8;  // 8 bf16 (MFMA K=32 A/B frag)
typedef __attribute__((ext_vector_type(4))) short bf16x4;  // 4 bf16 (MFMA K=16 A/B frag)
typedef __attribute__((ext_vector_type(4))) float f32x4;   // MFMA C/D frag

// __has_builtin for amdgcn builtins is false in the HOST pass; device-only check.
#if defined(__HIP_DEVICE_COMPILE__) && !__has_builtin(__builtin_amdgcn_mfma_f32_16x16x16bf16_1k)
#error "mfma_f32_16x16x16bf16_1k required on gfx950"
#endif
#define MFMA16(a, b, c) __builtin_amdgcn_mfma_f32_16x16x16bf16_1k(a, b, c, 0, 0, 0)
#define MFMA32(a, b, c) __builtin_amdgcn_mfma_f32_16x16x32_bf16(a, b, c, 0, 0, 0)

__device__ __forceinline__ unsigned short f2bf(float f) {
  union { float f; unsigned int u; } v; v.f = f;
  unsigned int u = v.u;
  u = u + 0x7fffu + ((u >> 16) & 1u);   // round-nearest-even
  return (unsigned short)(u >> 16);
}

// async global(16B/lane) -> LDS (wave-uniform dest base + lane*16)
__device__ __forceinline__ void gload16(const void* g, void* l) {
  __builtin_amdgcn_global_load_lds(
      (const __attribute__((address_space(1))) unsigned int*)g,
      (__attribute__((address_space(3))) unsigned int*)l, 16, 0, 0);
}

// ---------------------------------------------------------------------------
// k_prep: Wt[m][h][c] = W_m[c][h] as bf16.  grid=192 (m*64+h), block=256.
// ---------------------------------------------------------------------------
__global__ __launch_bounds__(256) void k_prep(const float* __restrict__ Wq,
                                              const float* __restrict__ Wk,
                                              const float* __restrict__ Wv,
                                              unsigned short* __restrict__ Wt) {
  const int m = blockIdx.x >> 6;
  const int h = blockIdx.x & 63;
  const float* W = (m == 0) ? Wq : (m == 1) ? Wk : Wv;
  const int tid = threadIdx.x;
  unsigned short* dst = Wt + ((size_t)(m * 64 + h)) * 1024;
#pragma unroll
  for (int j = 0; j < 4; ++j) {
    int c = j * 256 + tid;
    dst[c] = f2bf(W[(size_t)c * 64 + h]);
  }
}

// ---------------------------------------------------------------------------
// k_qkv: C[16384x192] = x * W (Q|K|V), bf16 MFMA.
// R5-proven staging structure (simple: load->cvt->ds_write->barrier->MFMA,
// all liveness within one iteration -> no spill), reshaped for OCCUPANCY:
// 16-row x 192-col tiles, grid 1024, launch_bounds(256,4) -> 4 blocks/CU
// resident (29.3KB LDS x4 = 117KB). Theory: x (64MB HBM, the cost) was
// issued in barrier-gated bursts with too few bytes in flight per CU
// (~2.5 TB/s effective at 2 blocks/CU = R5's 27us); 4 blocks/CU doubles
// issue concurrency -> ~5-6 TB/s -> ~13-17us.
// Each wave: 16 rows x 48 cols (wid = col group), acc[3].
// ---------------------------------------------------------------------------
__global__ __launch_bounds__(256, 4) void k_qkv(const float* __restrict__ x,
                                                const unsigned short* __restrict__ Wt,
                                                unsigned short* __restrict__ Q,
                                                unsigned short* __restrict__ K,
                                                unsigned short* __restrict__ Vt) {
  // xs[16][72] (2304B) | wsh[192][72] (27648B); os[16][200] aliases for epilogue.
  __shared__ __align__(16) char smem[29952];
  unsigned short (*xs)[72] = (unsigned short (*)[72])smem;
  unsigned short (*wsh)[72] = (unsigned short (*)[72])(smem + 2304);
  unsigned short (*os)[200] = (unsigned short (*)[200])smem;

  const int tid = threadIdx.x;
  const int lane = tid & 63;
  const int wid = tid >> 6;           // col group: cols 48*wid .. 48*wid+47
  const int l15 = lane & 15, g = lane >> 4;
  const int r0 = blockIdx.x * 16;

  f32x4 acc[3];
#pragma unroll
  for (int j = 0; j < 3; ++j)
#pragma unroll
    for (int r = 0; r < 4; ++r) acc[j][r] = 0.f;

  const int xrow = tid >> 4;          // 0..15
  const int xc = (tid & 15) * 4;      // 0..60

  for (int kt = 0; kt < 16; ++kt) {
    const int k0 = kt * 64;
    // x stage: 1 float4 per thread, fp32 -> bf16 (liveness dies at ds_write)
    {
      float4 v = *(const float4*)(x + (size_t)(r0 + xrow) * 1024 + k0 + xc);
      ushort4 bv;
      bv.x = f2bf(v.x); bv.y = f2bf(v.y); bv.z = f2bf(v.z); bv.w = f2bf(v.w);
      *(ushort4*)&xs[xrow][xc] = bv;
    }
    // W stage: 192 rows x 64 k bf16, 6 uint4 per thread (R5-proven pattern)
#pragma unroll
    for (int j = 0; j < 6; ++j) {
      int u = j * 256 + tid;
      int row = u >> 3, ch = u & 7;
      uint4 w = *(const uint4*)(Wt + (size_t)row * 1024 + k0 + ch * 8);
      *(uint4*)&wsh[row][ch * 8] = w;
    }
    __syncthreads();
#pragma unroll
    for (int kf = 0; kf < 2; ++kf) {
      bf16x8 a = *(const bf16x8*)&xs[l15][kf * 32 + g * 8];
#pragma unroll
      for (int nf = 0; nf < 3; ++nf) {
        bf16x8 bfr = *(const bf16x8*)&wsh[wid * 48 + nf * 16 + l15][kf * 32 + g * 8];
        acc[nf] = MFMA32(a, bfr, acc[nf]);
      }
    }
    __syncthreads();
  }

  // epilogue: acc -> os (bf16). D layout: col = l15, row = 4g+r.
#pragma unroll
  for (int nf = 0; nf < 3; ++nf)
#pragma unroll
    for (int r = 0; r < 4; ++r)
      os[4 * g + r][wid * 48 + nf * 16 + l15] = f2bf(acc[nf][r]);
  __syncthreads();

  const int b = r0 >> 11;
  const int t0 = r0 & 2047;
  // Q, K: 16 rows x 8 chunks = 128 uint4 each; waves 0-1 -> Q, 2-3 -> K
  {
    int u = tid & 127;
    int row = u >> 3, ch = u & 7;
    if (tid < 128)
      *(uint4*)(Q + (size_t)(r0 + row) * 64 + ch * 8) = *(const uint4*)&os[row][ch * 8];
    else
      *(uint4*)(K + (size_t)(r0 + row) * 64 + ch * 8) = *(const uint4*)&os[row][64 + ch * 8];
  }
  // Vt transpose: 64 h x 16 t; each thread 4 t-values (8B store)
  {
    int h = tid >> 2, qd = tid & 3;
    unsigned short tmp[4];
#pragma unroll
    for (int r = 0; r < 4; ++r) tmp[r] = os[qd * 4 + r][128 + h];
    *(ushort4*)(Vt + ((size_t)b * 64 + h) * 2048 + t0 + qd * 4) = *(const ushort4*)tmp;
  }
}

// ---------------------------------------------------------------------------
// k_attn_coop: block-cooperative flash attention. UNCHANGED from R7/R8/R9
// (est ~10-12us: (256,3), XCD-bijective swizzle, gload_lds dbuf staging).
// ---------------------------------------------------------------------------
__global__ __launch_bounds__(256, 3) void k_attn_coop(const unsigned short* __restrict__ Q,
                                                      const unsigned short* __restrict__ K,
                                                      const unsigned short* __restrict__ Vt,
                                                      float* __restrict__ out,
                                                      float* __restrict__ po,
                                                      float* __restrict__ pml) {
  __shared__ __align__(16) unsigned short lds[2][8192];  // [buf][K 4096sh | V 4096sh]

  const int tid = threadIdx.x;
  const int lane = tid & 63;
  const int l15 = lane & 15, g = lane >> 4;
  const int wid = __builtin_amdgcn_readfirstlane(tid >> 6);

  // ---- task decode with XCD swizzle (1152 = 8 XCD x 144 tasks/batch) ----
  const int raw = blockIdx.x;
  const int bi = (raw & 7) * 144 + (raw >> 3);
  const int b = bi / 144;
  const int id = bi - b * 144;
  int gq = 0;
#pragma unroll
  for (int t = 1; t < 8; ++t)
    if (id >= 2 * t * (t + 1)) gq = t;
  const int rem = id - 2 * gq * (gq + 1);
  const int ql = rem / (gq + 1);
  const int s = rem - ql * (gq + 1);
  const int qt = 4 * gq + ql;          // 64-row q-tile 0..31
  const int qblk = qt * 64;
  const int klo = 256 * s;
  const int khi = min(klo + 256, qblk + 64);
  const int nt = (khi - klo + 63) >> 6;
  const int q0w = qblk + wid * 16;     // this wave's q rows

  const unsigned short* Qb = Q + (size_t)b * Tn * Hn;
  const unsigned short* Kb = K + (size_t)b * Tn * Hn;
  const unsigned short* Vb = Vt + (size_t)b * Hn * Tn;

  // Q as B-operand: lane l15 = q row, k = 8g+j
  bf16x8 bq0 = *(const bf16x8*)(Qb + (size_t)(q0w + l15) * 64 + g * 8);
  bf16x8 bq1 = *(const bf16x8*)(Qb + (size_t)(q0w + l15) * 64 + 32 + g * 8);

  f32x4 o[4];
#pragma unroll
  for (int hf = 0; hf < 4; ++hf)
#pragma unroll
    for (int r = 0; r < 4; ++r) o[hf][r] = 0.f;
  float m = -1e30f, lsum = 0.f;
  const float sc = 0.03125f * 1.44269504088896f;  // C^-0.5 * log2(e)

  // stage one 64-key tile: K[64key][64d] + V[64h][64key], swizzled granules.
  auto stage = [&](int buf, int k0) {
    unsigned short* tb = &lds[buf][0];
#pragma unroll
    for (int j = 0; j < 4; ++j) {
      const int p = wid * 256 + j * 64 + lane;
      const unsigned short* src;
      if (wid < 2) {                       // K: rows = keys
        const int row = p >> 3, c = p & 7;
        src = Kb + (size_t)(k0 + row) * 64 + ((c ^ (row & 7)) * 8);
      } else {                             // V: rows = h
        const int q = p - 512;
        const int h = q >> 3, c = q & 7;
        src = Vb + (size_t)h * Tn + k0 + ((c ^ (h & 7)) * 8);
      }
      gload16(src, tb + wid * 2048 + j * 512);
    }
  };

  stage(0, klo);
  __syncthreads();

  for (int t = 0; t < nt; ++t) {
    const int cur = t & 1;
    const int k0 = klo + t * 64;
    if (t + 1 < nt) stage(cur ^ 1, klo + (t + 1) * 64);

    const unsigned short* kt = &lds[cur][0];
    const unsigned short* vt = &lds[cur][4096];

    // S^T: lane l15 = q, reg (kc, 4g+r) = key
    f32x4 sacc[4];
#pragma unroll
    for (int kc = 0; kc < 4; ++kc) {
      const int row = kc * 16 + l15;
      const int sw = row & 7;
      bf16x8 ka = *(const bf16x8*)&kt[row * 64 + ((g ^ sw) * 8)];
      bf16x8 kb2 = *(const bf16x8*)&kt[row * 64 + (((4 + g) ^ sw) * 8)];
#pragma unroll
      for (int r = 0; r < 4; ++r) sacc[kc][r] = 0.f;
      sacc[kc] = MFMA32(ka, bq0, sacc[kc]);
      sacc[kc] = MFMA32(kb2, bq1, sacc[kc]);
    }
    // scale + causal mask (key <= q); boundary tiles only (wave-uniform)
    float sv[4][4];
    if (k0 + 63 > q0w) {
      const int q = q0w + l15;
#pragma unroll
      for (int kc = 0; kc < 4; ++kc)
#pragma unroll
        for (int r = 0; r < 4; ++r) {
          int key = k0 + kc * 16 + 4 * g + r;
          sv[kc][r] = (key <= q) ? sacc[kc][r] * sc : -1e30f;
        }
    } else {
#pragma unroll
      for (int kc = 0; kc < 4; ++kc)
#pragma unroll
        for (int r = 0; r < 4; ++r) sv[kc][r] = sacc[kc][r] * sc;
    }
    // defer-max: lane-local max suffices for the trigger test
    float pm = sv[0][0];
#pragma unroll
    for (int kc = 0; kc < 4; ++kc)
#pragma unroll
      for (int r = 0; r < 4; ++r) pm = fmaxf(pm, sv[kc][r]);
    if (__any(pm > m + 8.f)) {
      pm = fmaxf(pm, __shfl_xor(pm, 16));
      pm = fmaxf(pm, __shfl_xor(pm, 32));
      float mn = fmaxf(m, pm);
      float alpha = exp2f(m - mn);
      lsum *= alpha;
      float an[4];
#pragma unroll
      for (int r = 0; r < 4; ++r) an[r] = __shfl(alpha, 4 * g + r);
#pragma unroll
      for (int hf = 0; hf < 4; ++hf)
#pragma unroll
        for (int r = 0; r < 4; ++r) o[hf][r] *= an[r];
      m = mn;
    }
    float ts = 0.f;
#pragma unroll
    for (int kc = 0; kc < 4; ++kc)
#pragma unroll
      for (int r = 0; r < 4; ++r) { sv[kc][r] = exp2f(sv[kc][r] - m); ts += sv[kc][r]; }
    ts += __shfl_xor(ts, 16);
    ts += __shfl_xor(ts, 32);
    lsum += ts;
    // P in K=16 A-operand layout: lane l15 = q, k-local = 4g+r
    bf16x4 pa[4];
#pragma unroll
    for (int kc = 0; kc < 4; ++kc) {
      pa[kc][0] = (short)f2bf(sv[kc][0]); pa[kc][1] = (short)f2bf(sv[kc][1]);
      pa[kc][2] = (short)f2bf(sv[kc][2]); pa[kc][3] = (short)f2bf(sv[kc][3]);
    }
    // V frags from LDS: B-operand lane l15 = h col, k-local = 4g+r
    bf16x4 vf[4][4];
#pragma unroll
    for (int hf = 0; hf < 4; ++hf) {
      const int h = hf * 16 + l15, hs = h & 7;
#pragma unroll
      for (int kc = 0; kc < 4; ++kc) {
        const int gran = (kc * 2 + (g >> 1)) ^ hs;
        vf[hf][kc] = *(const bf16x4*)&vt[h * 64 + gran * 8 + (g & 1) * 4];
      }
    }
#pragma unroll
    for (int hf = 0; hf < 4; ++hf)
#pragma unroll
      for (int kc = 0; kc < 4; ++kc)
        o[hf] = MFMA16(pa[kc], vf[hf][kc], o[hf]);

    __syncthreads();   // drains stage vmcnt + all waves done reading buf
  }

  if (qt >= 4) {
    // packed partial: slot = task id - 4 within batch
    const int slot = b * 140 + id - 4;
    float* pob = po + (size_t)slot * 4096;
#pragma unroll
    for (int hf = 0; hf < 4; ++hf)
#pragma unroll
      for (int r = 0; r < 4; ++r)
        pob[(16 * wid + 4 * g + r) * 64 + hf * 16 + l15] = o[hf][r];
    if (lane < 16) {
      pml[(size_t)slot * 128 + 16 * wid + l15] = m;
      pml[(size_t)slot * 128 + 64 + 16 * wid + l15] = lsum;
    }
  } else {
    const float il = 1.f / lsum;
    float iln[4];
#pragma unroll
    for (int r = 0; r < 4; ++r) iln[r] = __shfl(il, 4 * g + r);
    float* ob = out + ((size_t)b * Tn + q0w) * 64;
#pragma unroll
    for (int hf = 0; hf < 4; ++hf)
#pragma unroll
      for (int r = 0; r < 4; ++r)
        ob[(size_t)(4 * g + r) * 64 + hf * 16 + l15] = o[hf][r] * iln[r];
  }
}

// ---------------------------------------------------------------------------
// k_comb: merge 2..8 segments per (b, qt 4..31). grid=(28,8), block=256.
// ---------------------------------------------------------------------------
__global__ __launch_bounds__(256) void k_comb(const float* __restrict__ po,
                                              const float* __restrict__ pml,
                                              float* __restrict__ out) {
  const int qt = 4 + blockIdx.x;
  const int b = blockIdx.y;
  const int gq = qt >> 2, ql = qt & 3;
  const int nseg = gq + 1;
  const int base = b * 140 + 2 * gq * (gq + 1) + ql * (gq + 1) - 4;
  const int r = threadIdx.x >> 2;
  const int cg = threadIdx.x & 3;

  float mv[8], lv[8], M = -1e30f;
#pragma unroll
  for (int s = 0; s < 8; ++s)
    if (s < nseg) {
      mv[s] = pml[(size_t)(base + s) * 128 + r];
      lv[s] = pml[(size_t)(base + s) * 128 + 64 + r];
      M = fmaxf(M, mv[s]);
    }
  float w[8], L = 0.f;
#pragma unroll
  for (int s = 0; s < 8; ++s)
    if (s < nseg) { w[s] = exp2f(mv[s] - M); L += w[s] * lv[s]; }

  float acc[16];
#pragma unroll
  for (int c = 0; c < 16; ++c) acc[c] = 0.f;
#pragma unroll
  for (int s = 0; s < 8; ++s)
    if (s < nseg) {
      const float* pb = po + (size_t)(base + s) * 4096 + r * 64 + cg * 16;
#pragma unroll
      for (int j = 0; j < 4; ++j) {
        float4 v = *(const float4*)(pb + 4 * j);
        acc[4 * j + 0] += w[s] * v.x; acc[4 * j + 1] += w[s] * v.y;
        acc[4 * j + 2] += w[s] * v.z; acc[4 * j + 3] += w[s] * v.w;
      }
    }
  const float invL = 1.f / L;
  float* ob = out + ((size_t)b * Tn + qt * 64 + r) * 64 + cg * 16;
#pragma unroll
  for (int j = 0; j < 4; ++j) {
    float4 v;
    v.x = acc[4 * j + 0] * invL; v.y = acc[4 * j + 1] * invL;
    v.z = acc[4 * j + 2] * invL; v.w = acc[4 * j + 3] * invL;
    *(float4*)(ob + 4 * j) = v;
  }
}

// ---------------------------------------------------------------------------
// k_attn_wave: per-wave fallback (full key range), tiny workspace only.
// ---------------------------------------------------------------------------
__global__ __launch_bounds__(256, 2) void k_attn_wave(const unsigned short* __restrict__ Q,
                                                      const unsigned short* __restrict__ K,
                                                      const unsigned short* __restrict__ Vt,
                                                      float* __restrict__ out) {
  const int tid = threadIdx.x;
  const int lane = tid & 63;
  const int l15 = lane & 15, g = lane >> 4;
  const int wid = tid >> 6;
  const int task = blockIdx.x * 4 + wid;
  const int b = task >> 7, qt = task & 127;
  const int q0 = qt * 16;
  const int nt = (q0 + 16 + 63) >> 6;

  const unsigned short* Qb = Q + (size_t)b * Tn * Hn;
  const unsigned short* Kb = K + (size_t)b * Tn * Hn;
  const unsigned short* Vb = Vt + (size_t)b * Hn * Tn;

  bf16x8 bq0 = *(const bf16x8*)(Qb + (size_t)(q0 + l15) * 64 + g * 8);
  bf16x8 bq1 = *(const bf16x8*)(Qb + (size_t)(q0 + l15) * 64 + 32 + g * 8);

  f32x4 o[4];
#pragma unroll
  for (int hf = 0; hf < 4; ++hf)
#pragma unroll
    for (int r = 0; r < 4; ++r) o[hf][r] = 0.f;
  float m = -1e30f, lsum = 0.f;
  const float sc = 0.03125f * 1.44269504088896f;

  for (int t = 0; t < nt; ++t) {
    const int k0 = t * 64;
    bf16x4 vf[4][4];
#pragma unroll
    for (int hf = 0; hf < 4; ++hf) {
      const unsigned short* vrow = Vb + (size_t)(hf * 16 + l15) * Tn + k0 + 4 * g;
#pragma unroll
      for (int kc = 0; kc < 4; ++kc) vf[hf][kc] = *(const bf16x4*)(vrow + kc * 16);
    }
    f32x4 sacc[4];
#pragma unroll
    for (int kc = 0; kc < 4; ++kc) {
      const unsigned short* kp = Kb + (size_t)(k0 + kc * 16 + l15) * 64 + g * 8;
      bf16x8 ka = *(const bf16x8*)kp;
      bf16x8 kb2 = *(const bf16x8*)(kp + 32);
#pragma unroll
      for (int r = 0; r < 4; ++r) sacc[kc][r] = 0.f;
      sacc[kc] = MFMA32(ka, bq0, sacc[kc]);
      sacc[kc] = MFMA32(kb2, bq1, sacc[kc]);
    }
    float sv[4][4];
    if (k0 + 63 > q0) {
      const int q = q0 + l15;
#pragma unroll
      for (int kc = 0; kc < 4; ++kc)
#pragma unroll
        for (int r = 0; r < 4; ++r) {
          int key = k0 + kc * 16 + 4 * g + r;
          sv[kc][r] = (key <= q) ? sacc[kc][r] * sc : -1e30f;
        }
    } else {
#pragma unroll
      for (int kc = 0; kc < 4; ++kc)
#pragma unroll
        for (int r = 0; r < 4; ++r) sv[kc][r] = sacc[kc][r] * sc;
    }
    float pm = sv[0][0];
#pragma unroll
    for (int kc = 0; kc < 4; ++kc)
#pragma unroll
      for (int r = 0; r < 4; ++r) pm = fmaxf(pm, sv[kc][r]);
    if (__any(pm > m + 8.f)) {
      pm = fmaxf(pm, __shfl_xor(pm, 16));
      pm = fmaxf(pm, __shfl_xor(pm, 32));
      float mn = fmaxf(m, pm);
      float alpha = exp2f(m - mn);
      lsum *= alpha;
      float an[4];
#pragma unroll
      for (int r = 0; r < 4; ++r) an[r] = __shfl(alpha, 4 * g + r);
#pragma unroll
      for (int hf = 0; hf < 4; ++hf)
#pragma unroll
        for (int r = 0; r < 4; ++r) o[hf][r] *= an[r];
      m = mn;
    }
    float ts = 0.f;
#pragma unroll
    for (int kc = 0; kc < 4; ++kc)
#pragma unroll
      for (int r = 0; r < 4; ++r) { sv[kc][r] = exp2f(sv[kc][r] - m); ts += sv[kc][r]; }
    ts += __shfl_xor(ts, 16);
    ts += __shfl_xor(ts, 32);
    lsum += ts;
    bf16x4 pa[4];
#pragma unroll
    for (int kc = 0; kc < 4; ++kc) {
      pa[kc][0] = (short)f2bf(sv[kc][0]); pa[kc][1] = (short)f2bf(sv[kc][1]);
      pa[kc][2] = (short)f2bf(sv[kc][2]); pa[kc][3] = (short)f2bf(sv[kc][3]);
    }
#pragma unroll
    for (int hf = 0; hf < 4; ++hf)
#pragma unroll
      for (int kc = 0; kc < 4; ++kc)
        o[hf] = MFMA16(pa[kc], vf[hf][kc], o[hf]);
  }
  const float il = 1.f / lsum;
  float iln[4];
#pragma unroll
  for (int r = 0; r < 4; ++r) iln[r] = __shfl(il, 4 * g + r);
  float* ob = out + ((size_t)b * Tn + q0) * 64;
#pragma unroll
  for (int hf = 0; hf < 4; ++hf)
#pragma unroll
    for (int r = 0; r < 4; ++r)
      ob[(size_t)(4 * g + r) * 64 + hf * 16 + l15] = o[hf][r] * iln[r];
}

// ---------------------------------------------------------------------------
extern "C" void kernel_launch(void* const* d_in, const int* in_sizes, int n_in,
                              void* d_out, int out_size, void* d_ws, size_t ws_size,
                              hipStream_t stream) {
  const float* x  = (const float*)d_in[0];
  const float* Wq = (const float*)d_in[1];
  const float* Wk = (const float*)d_in[2];
  const float* Wv = (const float*)d_in[3];
  float* out = (float*)d_out;

  // ws layout (bf16): Wt[3*64*1024] | Q | K | Vt  (each B*T*64), then fp32 partials
  unsigned short* Wt = (unsigned short*)d_ws;
  unsigned short* Qs = Wt + 3 * 64 * 1024;
  unsigned short* Ks = Qs + (size_t)Bn * Tn * Hn;
  unsigned short* Vt = Ks + (size_t)Bn * Tn * Hn;
  const size_t bf_bytes = (3 * 64 * 1024 + 3 * (size_t)Bn * Tn * Hn) * 2;
  float* po = (float*)((char*)d_ws + bf_bytes);

  const size_t nslots = (size_t)Bn * 140;   // packed partial slots
  float* pml = po + nslots * 4096;
  const size_t need = bf_bytes + nslots * (4096 + 128) * sizeof(float);  // ~25 MB

  hipLaunchKernelGGL(k_prep, dim3(192), dim3(256), 0, stream, Wq, Wk, Wv, Wt);
  hipLaunchKernelGGL(k_qkv, dim3(1024), dim3(256), 0, stream, x, Wt, Qs, Ks, Vt);
  if (ws_size >= need) {
    hipLaunchKernelGGL(k_attn_coop, dim3(1152), dim3(256), 0, stream, Qs, Ks, Vt, out, po, pml);
    hipLaunchKernelGGL(k_comb, dim3(28, 8), dim3(256), 0, stream, po, pml, out);
  } else {
    hipLaunchKernelGGL(k_attn_wave, dim3(256), dim3(256), 0, stream, Qs, Ks, Vt, out);
  }
}

// Round 11
// 54.928 us; speedup vs baseline: 1.1004x; 1.1004x over previous
//
#include <hip/hip_runtime.h>
#include <hip/hip_bf16.h>
#include <stdint.h>

// Problem constants: B=8, T=2048, C=1024, H=64. Single-head causal attention.
#define Bn 8
#define Tn 2048
#define Cn 1024
#define Hn 64

typedef __attribute__((ext_vector_type(8))) short bf16x8;  // 8 bf16 (MFMA K=32 A/B frag)
typedef __attribute__((ext_vector_type(4))) short bf16x4;  // 4 bf16 (MFMA K=16 A/B frag)
typedef __attribute__((ext_vector_type(4))) float f32x4;   // MFMA C/D frag

// __has_builtin for amdgcn builtins is false in the HOST pass; device-only check.
#if defined(__HIP_DEVICE_COMPILE__) && !__has_builtin(__builtin_amdgcn_mfma_f32_16x16x16bf16_1k)
#error "mfma_f32_16x16x16bf16_1k required on gfx950"
#endif
#define MFMA16(a, b, c) __builtin_amdgcn_mfma_f32_16x16x16bf16_1k(a, b, c, 0, 0, 0)
#define MFMA32(a, b, c) __builtin_amdgcn_mfma_f32_16x16x32_bf16(a, b, c, 0, 0, 0)

__device__ __forceinline__ unsigned short f2bf(float f) {
  union { float f; unsigned int u; } v; v.f = f;
  unsigned int u = v.u;
  u = u + 0x7fffu + ((u >> 16) & 1u);   // round-nearest-even
  return (unsigned short)(u >> 16);
}

// async global(16B/lane) -> LDS (wave-uniform dest base + lane*16)
__device__ __forceinline__ void gload16(const void* g, void* l) {
  __builtin_amdgcn_global_load_lds(
      (const __attribute__((address_space(1))) unsigned int*)g,
      (__attribute__((address_space(3))) unsigned int*)l, 16, 0, 0);
}

// ---------------------------------------------------------------------------
// k_prep: Wt[m][h][c] = W_m[c][h] as bf16.  grid=192 (m*64+h), block=256.
// ---------------------------------------------------------------------------
__global__ __launch_bounds__(256) void k_prep(const float* __restrict__ Wq,
                                              const float* __restrict__ Wk,
                                              const float* __restrict__ Wv,
                                              unsigned short* __restrict__ Wt) {
  const int m = blockIdx.x >> 6;
  const int h = blockIdx.x & 63;
  const float* W = (m == 0) ? Wq : (m == 1) ? Wk : Wv;
  const int tid = threadIdx.x;
  unsigned short* dst = Wt + ((size_t)(m * 64 + h)) * 1024;
#pragma unroll
  for (int j = 0; j < 4; ++j) {
    int c = j * 256 + tid;
    dst[c] = f2bf(W[(size_t)c * 64 + h]);
  }
}

// ---------------------------------------------------------------------------
// k_qkv: EXACT R5 kernel (the measured-best variant, ~27us inferred from
// R5/R6 totals). 32-row x 192-col tiles, grid=512, block=256 (4 waves 2x2),
// single LDS stage, 2 barriers/iter, launch_bounds(256,2).
// Model from R4..R10: duration ~ W-restage volume (grid x 24.6KB x 16) at
// ~12-15 B/cyc/CU staged-load issue limit; this shape minimizes it among
// spill-free configs. Do NOT "improve" without a new mechanism (3 failures).
// ---------------------------------------------------------------------------
__global__ __launch_bounds__(256, 2) void k_qkv(const float* __restrict__ x,
                                                const unsigned short* __restrict__ Wt,
                                                unsigned short* __restrict__ Q,
                                                unsigned short* __restrict__ K,
                                                unsigned short* __restrict__ Vt) {
  // xs[32][72] | wsh[192][72]; os[32][200] aliases for the epilogue.
  __shared__ __align__(16) char smem[32256];
  unsigned short (*xs)[72] = (unsigned short (*)[72])smem;
  unsigned short (*wsh)[72] = (unsigned short (*)[72])(smem + 32 * 72 * 2);
  unsigned short (*os)[200] = (unsigned short (*)[200])smem;

  const int tid = threadIdx.x;
  const int lane = tid & 63;
  const int wid = tid >> 6;
  const int wm = wid >> 1, wn = wid & 1;
  const int l15 = lane & 15, g = lane >> 4;
  const int r0 = blockIdx.x * 32;

  f32x4 acc[6];
#pragma unroll
  for (int j = 0; j < 6; ++j)
#pragma unroll
    for (int r = 0; r < 4; ++r) acc[j][r] = 0.f;

  const int srow = tid >> 3;          // 0..31
  const int scol = (tid & 7) * 8;     // 0..56

  for (int kt = 0; kt < 16; ++kt) {
    const int k0 = kt * 64;
    // stage x (fp32 -> bf16): 32 rows x 64 k
    const float* xp = x + (size_t)(r0 + srow) * 1024 + k0 + scol;
    {
      float4 v0 = *(const float4*)xp;
      float4 v1 = *(const float4*)(xp + 4);
      ushort4 b0, b1;
      b0.x = f2bf(v0.x); b0.y = f2bf(v0.y); b0.z = f2bf(v0.z); b0.w = f2bf(v0.w);
      b1.x = f2bf(v1.x); b1.y = f2bf(v1.y); b1.z = f2bf(v1.z); b1.w = f2bf(v1.w);
      *(ushort4*)&xs[srow][scol] = b0;
      *(ushort4*)&xs[srow][scol + 4] = b1;
    }
    // stage Wt slice (192 rows x 64 k bf16)
#pragma unroll
    for (int j = 0; j < 6; ++j) {
      int u = j * 256 + tid;
      int row = u >> 3, ch = u & 7;
      uint4 w = *(const uint4*)(Wt + (size_t)row * 1024 + k0 + ch * 8);
      *(uint4*)&wsh[row][ch * 8] = w;
    }
    __syncthreads();
#pragma unroll
    for (int kf = 0; kf < 2; ++kf) {
      bf16x8 a = *(const bf16x8*)&xs[wm * 16 + l15][kf * 32 + g * 8];
#pragma unroll
      for (int nf = 0; nf < 6; ++nf) {
        bf16x8 bfr = *(const bf16x8*)&wsh[wn * 96 + nf * 16 + l15][kf * 32 + g * 8];
        acc[nf] = MFMA32(a, bfr, acc[nf]);
      }
    }
    __syncthreads();
  }

  // epilogue: acc -> os (bf16). D layout: col = l&15, row = 4*(l>>4)+reg.
#pragma unroll
  for (int nf = 0; nf < 6; ++nf)
#pragma unroll
    for (int r = 0; r < 4; ++r)
      os[wm * 16 + 4 * g + r][wn * 96 + nf * 16 + l15] = f2bf(acc[nf][r]);
  __syncthreads();

  const int b = r0 >> 11;
  const int t0 = r0 & 2047;
  {
    int row = tid >> 3, ch = tid & 7;
    *(uint4*)(Q + (size_t)(r0 + row) * 64 + ch * 8) = *(const uint4*)&os[row][ch * 8];
    *(uint4*)(K + (size_t)(r0 + row) * 64 + ch * 8) = *(const uint4*)&os[row][64 + ch * 8];
  }
  {
    int h = tid >> 2, tc = (tid & 3) * 8;
    unsigned short tmp[8];
#pragma unroll
    for (int r = 0; r < 8; ++r) tmp[r] = os[tc + r][128 + h];
    *(uint4*)(Vt + ((size_t)b * 64 + h) * 2048 + t0 + tc) = *(const uint4*)tmp;
  }
}

// ---------------------------------------------------------------------------
// k_attn_coop: block-cooperative flash attention. UNCHANGED from R7-R10
// (est ~10-12us: (256,3), XCD-bijective swizzle, gload_lds dbuf staging).
// ---------------------------------------------------------------------------
__global__ __launch_bounds__(256, 3) void k_attn_coop(const unsigned short* __restrict__ Q,
                                                      const unsigned short* __restrict__ K,
                                                      const unsigned short* __restrict__ Vt,
                                                      float* __restrict__ out,
                                                      float* __restrict__ po,
                                                      float* __restrict__ pml) {
  __shared__ __align__(16) unsigned short lds[2][8192];  // [buf][K 4096sh | V 4096sh]

  const int tid = threadIdx.x;
  const int lane = tid & 63;
  const int l15 = lane & 15, g = lane >> 4;
  const int wid = __builtin_amdgcn_readfirstlane(tid >> 6);

  // ---- task decode with XCD swizzle (1152 = 8 XCD x 144 tasks/batch) ----
  const int raw = blockIdx.x;
  const int bi = (raw & 7) * 144 + (raw >> 3);
  const int b = bi / 144;
  const int id = bi - b * 144;
  int gq = 0;
#pragma unroll
  for (int t = 1; t < 8; ++t)
    if (id >= 2 * t * (t + 1)) gq = t;
  const int rem = id - 2 * gq * (gq + 1);
  const int ql = rem / (gq + 1);
  const int s = rem - ql * (gq + 1);
  const int qt = 4 * gq + ql;          // 64-row q-tile 0..31
  const int qblk = qt * 64;
  const int klo = 256 * s;
  const int khi = min(klo + 256, qblk + 64);
  const int nt = (khi - klo + 63) >> 6;
  const int q0w = qblk + wid * 16;     // this wave's q rows

  const unsigned short* Qb = Q + (size_t)b * Tn * Hn;
  const unsigned short* Kb = K + (size_t)b * Tn * Hn;
  const unsigned short* Vb = Vt + (size_t)b * Hn * Tn;

  // Q as B-operand: lane l15 = q row, k = 8g+j
  bf16x8 bq0 = *(const bf16x8*)(Qb + (size_t)(q0w + l15) * 64 + g * 8);
  bf16x8 bq1 = *(const bf16x8*)(Qb + (size_t)(q0w + l15) * 64 + 32 + g * 8);

  f32x4 o[4];
#pragma unroll
  for (int hf = 0; hf < 4; ++hf)
#pragma unroll
    for (int r = 0; r < 4; ++r) o[hf][r] = 0.f;
  float m = -1e30f, lsum = 0.f;
  const float sc = 0.03125f * 1.44269504088896f;  // C^-0.5 * log2(e)

  // stage one 64-key tile: K[64key][64d] + V[64h][64key], swizzled granules.
  auto stage = [&](int buf, int k0) {
    unsigned short* tb = &lds[buf][0];
#pragma unroll
    for (int j = 0; j < 4; ++j) {
      const int p = wid * 256 + j * 64 + lane;
      const unsigned short* src;
      if (wid < 2) {                       // K: rows = keys
        const int row = p >> 3, c = p & 7;
        src = Kb + (size_t)(k0 + row) * 64 + ((c ^ (row & 7)) * 8);
      } else {                             // V: rows = h
        const int q = p - 512;
        const int h = q >> 3, c = q & 7;
        src = Vb + (size_t)h * Tn + k0 + ((c ^ (h & 7)) * 8);
      }
      gload16(src, tb + wid * 2048 + j * 512);
    }
  };

  stage(0, klo);
  __syncthreads();

  for (int t = 0; t < nt; ++t) {
    const int cur = t & 1;
    const int k0 = klo + t * 64;
    if (t + 1 < nt) stage(cur ^ 1, klo + (t + 1) * 64);

    const unsigned short* kt = &lds[cur][0];
    const unsigned short* vt = &lds[cur][4096];

    // S^T: lane l15 = q, reg (kc, 4g+r) = key
    f32x4 sacc[4];
#pragma unroll
    for (int kc = 0; kc < 4; ++kc) {
      const int row = kc * 16 + l15;
      const int sw = row & 7;
      bf16x8 ka = *(const bf16x8*)&kt[row * 64 + ((g ^ sw) * 8)];
      bf16x8 kb2 = *(const bf16x8*)&kt[row * 64 + (((4 + g) ^ sw) * 8)];
#pragma unroll
      for (int r = 0; r < 4; ++r) sacc[kc][r] = 0.f;
      sacc[kc] = MFMA32(ka, bq0, sacc[kc]);
      sacc[kc] = MFMA32(kb2, bq1, sacc[kc]);
    }
    // scale + causal mask (key <= q); boundary tiles only (wave-uniform)
    float sv[4][4];
    if (k0 + 63 > q0w) {
      const int q = q0w + l15;
#pragma unroll
      for (int kc = 0; kc < 4; ++kc)
#pragma unroll
        for (int r = 0; r < 4; ++r) {
          int key = k0 + kc * 16 + 4 * g + r;
          sv[kc][r] = (key <= q) ? sacc[kc][r] * sc : -1e30f;
        }
    } else {
#pragma unroll
      for (int kc = 0; kc < 4; ++kc)
#pragma unroll
        for (int r = 0; r < 4; ++r) sv[kc][r] = sacc[kc][r] * sc;
    }
    // defer-max: lane-local max suffices for the trigger test
    float pm = sv[0][0];
#pragma unroll
    for (int kc = 0; kc < 4; ++kc)
#pragma unroll
      for (int r = 0; r < 4; ++r) pm = fmaxf(pm, sv[kc][r]);
    if (__any(pm > m + 8.f)) {
      pm = fmaxf(pm, __shfl_xor(pm, 16));
      pm = fmaxf(pm, __shfl_xor(pm, 32));
      float mn = fmaxf(m, pm);
      float alpha = exp2f(m - mn);
      lsum *= alpha;
      float an[4];
#pragma unroll
      for (int r = 0; r < 4; ++r) an[r] = __shfl(alpha, 4 * g + r);
#pragma unroll
      for (int hf = 0; hf < 4; ++hf)
#pragma unroll
        for (int r = 0; r < 4; ++r) o[hf][r] *= an[r];
      m = mn;
    }
    float ts = 0.f;
#pragma unroll
    for (int kc = 0; kc < 4; ++kc)
#pragma unroll
      for (int r = 0; r < 4; ++r) { sv[kc][r] = exp2f(sv[kc][r] - m); ts += sv[kc][r]; }
    ts += __shfl_xor(ts, 16);
    ts += __shfl_xor(ts, 32);
    lsum += ts;
    // P in K=16 A-operand layout: lane l15 = q, k-local = 4g+r
    bf16x4 pa[4];
#pragma unroll
    for (int kc = 0; kc < 4; ++kc) {
      pa[kc][0] = (short)f2bf(sv[kc][0]); pa[kc][1] = (short)f2bf(sv[kc][1]);
      pa[kc][2] = (short)f2bf(sv[kc][2]); pa[kc][3] = (short)f2bf(sv[kc][3]);
    }
    // V frags from LDS: B-operand lane l15 = h col, k-local = 4g+r
    bf16x4 vf[4][4];
#pragma unroll
    for (int hf = 0; hf < 4; ++hf) {
      const int h = hf * 16 + l15, hs = h & 7;
#pragma unroll
      for (int kc = 0; kc < 4; ++kc) {
        const int gran = (kc * 2 + (g >> 1)) ^ hs;
        vf[hf][kc] = *(const bf16x4*)&vt[h * 64 + gran * 8 + (g & 1) * 4];
      }
    }
#pragma unroll
    for (int hf = 0; hf < 4; ++hf)
#pragma unroll
      for (int kc = 0; kc < 4; ++kc)
        o[hf] = MFMA16(pa[kc], vf[hf][kc], o[hf]);

    __syncthreads();   // drains stage vmcnt + all waves done reading buf
  }

  if (qt >= 4) {
    // packed partial: slot = task id - 4 within batch
    const int slot = b * 140 + id - 4;
    float* pob = po + (size_t)slot * 4096;
#pragma unroll
    for (int hf = 0; hf < 4; ++hf)
#pragma unroll
      for (int r = 0; r < 4; ++r)
        pob[(16 * wid + 4 * g + r) * 64 + hf * 16 + l15] = o[hf][r];
    if (lane < 16) {
      pml[(size_t)slot * 128 + 16 * wid + l15] = m;
      pml[(size_t)slot * 128 + 64 + 16 * wid + l15] = lsum;
    }
  } else {
    const float il = 1.f / lsum;
    float iln[4];
#pragma unroll
    for (int r = 0; r < 4; ++r) iln[r] = __shfl(il, 4 * g + r);
    float* ob = out + ((size_t)b * Tn + q0w) * 64;
#pragma unroll
    for (int hf = 0; hf < 4; ++hf)
#pragma unroll
      for (int r = 0; r < 4; ++r)
        ob[(size_t)(4 * g + r) * 64 + hf * 16 + l15] = o[hf][r] * iln[r];
  }
}

// ---------------------------------------------------------------------------
// k_comb: merge 2..8 segments per (b, qt 4..31). grid=(28,8), block=256.
// ---------------------------------------------------------------------------
__global__ __launch_bounds__(256) void k_comb(const float* __restrict__ po,
                                              const float* __restrict__ pml,
                                              float* __restrict__ out) {
  const int qt = 4 + blockIdx.x;
  const int b = blockIdx.y;
  const int gq = qt >> 2, ql = qt & 3;
  const int nseg = gq + 1;
  const int base = b * 140 + 2 * gq * (gq + 1) + ql * (gq + 1) - 4;
  const int r = threadIdx.x >> 2;
  const int cg = threadIdx.x & 3;

  float mv[8], lv[8], M = -1e30f;
#pragma unroll
  for (int s = 0; s < 8; ++s)
    if (s < nseg) {
      mv[s] = pml[(size_t)(base + s) * 128 + r];
      lv[s] = pml[(size_t)(base + s) * 128 + 64 + r];
      M = fmaxf(M, mv[s]);
    }
  float w[8], L = 0.f;
#pragma unroll
  for (int s = 0; s < 8; ++s)
    if (s < nseg) { w[s] = exp2f(mv[s] - M); L += w[s] * lv[s]; }

  float acc[16];
#pragma unroll
  for (int c = 0; c < 16; ++c) acc[c] = 0.f;
#pragma unroll
  for (int s = 0; s < 8; ++s)
    if (s < nseg) {
      const float* pb = po + (size_t)(base + s) * 4096 + r * 64 + cg * 16;
#pragma unroll
      for (int j = 0; j < 4; ++j) {
        float4 v = *(const float4*)(pb + 4 * j);
        acc[4 * j + 0] += w[s] * v.x; acc[4 * j + 1] += w[s] * v.y;
        acc[4 * j + 2] += w[s] * v.z; acc[4 * j + 3] += w[s] * v.w;
      }
    }
  const float invL = 1.f / L;
  float* ob = out + ((size_t)b * Tn + qt * 64 + r) * 64 + cg * 16;
#pragma unroll
  for (int j = 0; j < 4; ++j) {
    float4 v;
    v.x = acc[4 * j + 0] * invL; v.y = acc[4 * j + 1] * invL;
    v.z = acc[4 * j + 2] * invL; v.w = acc[4 * j + 3] * invL;
    *(float4*)(ob + 4 * j) = v;
  }
}

// ---------------------------------------------------------------------------
// k_attn_wave: per-wave fallback (full key range), tiny workspace only.
// ---------------------------------------------------------------------------
__global__ __launch_bounds__(256, 2) void k_attn_wave(const unsigned short* __restrict__ Q,
                                                      const unsigned short* __restrict__ K,
                                                      const unsigned short* __restrict__ Vt,
                                                      float* __restrict__ out) {
  const int tid = threadIdx.x;
  const int lane = tid & 63;
  const int l15 = lane & 15, g = lane >> 4;
  const int wid = tid >> 6;
  const int task = blockIdx.x * 4 + wid;
  const int b = task >> 7, qt = task & 127;
  const int q0 = qt * 16;
  const int nt = (q0 + 16 + 63) >> 6;

  const unsigned short* Qb = Q + (size_t)b * Tn * Hn;
  const unsigned short* Kb = K + (size_t)b * Tn * Hn;
  const unsigned short* Vb = Vt + (size_t)b * Hn * Tn;

  bf16x8 bq0 = *(const bf16x8*)(Qb + (size_t)(q0 + l15) * 64 + g * 8);
  bf16x8 bq1 = *(const bf16x8*)(Qb + (size_t)(q0 + l15) * 64 + 32 + g * 8);

  f32x4 o[4];
#pragma unroll
  for (int hf = 0; hf < 4; ++hf)
#pragma unroll
    for (int r = 0; r < 4; ++r) o[hf][r] = 0.f;
  float m = -1e30f, lsum = 0.f;
  const float sc = 0.03125f * 1.44269504088896f;

  for (int t = 0; t < nt; ++t) {
    const int k0 = t * 64;
    bf16x4 vf[4][4];
#pragma unroll
    for (int hf = 0; hf < 4; ++hf) {
      const unsigned short* vrow = Vb + (size_t)(hf * 16 + l15) * Tn + k0 + 4 * g;
#pragma unroll
      for (int kc = 0; kc < 4; ++kc) vf[hf][kc] = *(const bf16x4*)(vrow + kc * 16);
    }
    f32x4 sacc[4];
#pragma unroll
    for (int kc = 0; kc < 4; ++kc) {
      const unsigned short* kp = Kb + (size_t)(k0 + kc * 16 + l15) * 64 + g * 8;
      bf16x8 ka = *(const bf16x8*)kp;
      bf16x8 kb2 = *(const bf16x8*)(kp + 32);
#pragma unroll
      for (int r = 0; r < 4; ++r) sacc[kc][r] = 0.f;
      sacc[kc] = MFMA32(ka, bq0, sacc[kc]);
      sacc[kc] = MFMA32(kb2, bq1, sacc[kc]);
    }
    float sv[4][4];
    if (k0 + 63 > q0) {
      const int q = q0 + l15;
#pragma unroll
      for (int kc = 0; kc < 4; ++kc)
#pragma unroll
        for (int r = 0; r < 4; ++r) {
          int key = k0 + kc * 16 + 4 * g + r;
          sv[kc][r] = (key <= q) ? sacc[kc][r] * sc : -1e30f;
        }
    } else {
#pragma unroll
      for (int kc = 0; kc < 4; ++kc)
#pragma unroll
        for (int r = 0; r < 4; ++r) sv[kc][r] = sacc[kc][r] * sc;
    }
    float pm = sv[0][0];
#pragma unroll
    for (int kc = 0; kc < 4; ++kc)
#pragma unroll
      for (int r = 0; r < 4; ++r) pm = fmaxf(pm, sv[kc][r]);
    if (__any(pm > m + 8.f)) {
      pm = fmaxf(pm, __shfl_xor(pm, 16));
      pm = fmaxf(pm, __shfl_xor(pm, 32));
      float mn = fmaxf(m, pm);
      float alpha = exp2f(m - mn);
      lsum *= alpha;
      float an[4];
#pragma unroll
      for (int r = 0; r < 4; ++r) an[r] = __shfl(alpha, 4 * g + r);
#pragma unroll
      for (int hf = 0; hf < 4; ++hf)
#pragma unroll
        for (int r = 0; r < 4; ++r) o[hf][r] *= an[r];
      m = mn;
    }
    float ts = 0.f;
#pragma unroll
    for (int kc = 0; kc < 4; ++kc)
#pragma unroll
      for (int r = 0; r < 4; ++r) { sv[kc][r] = exp2f(sv[kc][r] - m); ts += sv[kc][r]; }
    ts += __shfl_xor(ts, 16);
    ts += __shfl_xor(ts, 32);
    lsum += ts;
    bf16x4 pa[4];
#pragma unroll
    for (int kc = 0; kc < 4; ++kc) {
      pa[kc][0] = (short)f2bf(sv[kc][0]); pa[kc][1] = (short)f2bf(sv[kc][1]);
      pa[kc][2] = (short)f2bf(sv[kc][2]); pa[kc][3] = (short)f2bf(sv[kc][3]);
    }
#pragma unroll
    for (int hf = 0; hf < 4; ++hf)
#pragma unroll
      for (int kc = 0; kc < 4; ++kc)
        o[hf] = MFMA16(pa[kc], vf[hf][kc], o[hf]);
  }
  const float il = 1.f / lsum;
  float iln[4];
#pragma unroll
  for (int r = 0; r < 4; ++r) iln[r] = __shfl(il, 4 * g + r);
  float* ob = out + ((size_t)b * Tn + q0) * 64;
#pragma unroll
  for (int hf = 0; hf < 4; ++hf)
#pragma unroll
    for (int r = 0; r < 4; ++r)
      ob[(size_t)(4 * g + r) * 64 + hf * 16 + l15] = o[hf][r] * iln[r];
}

// ---------------------------------------------------------------------------
extern "C" void kernel_launch(void* const* d_in, const int* in_sizes, int n_in,
                              void* d_out, int out_size, void* d_ws, size_t ws_size,
                              hipStream_t stream) {
  const float* x  = (const float*)d_in[0];
  const float* Wq = (const float*)d_in[1];
  const float* Wk = (const float*)d_in[2];
  const float* Wv = (const float*)d_in[3];
  float* out = (float*)d_out;

  // ws layout (bf16): Wt[3*64*1024] | Q | K | Vt  (each B*T*64), then fp32 partials
  unsigned short* Wt = (unsigned short*)d_ws;
  unsigned short* Qs = Wt + 3 * 64 * 1024;
  unsigned short* Ks = Qs + (size_t)Bn * Tn * Hn;
  unsigned short* Vt = Ks + (size_t)Bn * Tn * Hn;
  const size_t bf_bytes = (3 * 64 * 1024 + 3 * (size_t)Bn * Tn * Hn) * 2;
  float* po = (float*)((char*)d_ws + bf_bytes);

  const size_t nslots = (size_t)Bn * 140;   // packed partial slots
  float* pml = po + nslots * 4096;
  const size_t need = bf_bytes + nslots * (4096 + 128) * sizeof(float);  // ~25 MB

  hipLaunchKernelGGL(k_prep, dim3(192), dim3(256), 0, stream, Wq, Wk, Wv, Wt);
  hipLaunchKernelGGL(k_qkv, dim3(512), dim3(256), 0, stream, x, Wt, Qs, Ks, Vt);
  if (ws_size >= need) {
    hipLaunchKernelGGL(k_attn_coop, dim3(1152), dim3(256), 0, stream, Qs, Ks, Vt, out, po, pml);
    hipLaunchKernelGGL(k_comb, dim3(28, 8), dim3(256), 0, stream, po, pml, out);
  } else {
    hipLaunchKernelGGL(k_attn_wave, dim3(256), dim3(256), 0, stream, Qs, Ks, Vt, out);
  }
}

// Round 12
// 53.800 us; speedup vs baseline: 1.1235x; 1.0210x over previous
//
#include <hip/hip_runtime.h>
#include <hip/hip_bf16.h>
#include <stdint.h>

// Problem constants: B=8, T=2048, C=1024, H=64. Single-head causal attention.
#define Bn 8
#define Tn 2048
#define Cn 1024
#define Hn 64

typedef __attribute__((ext_vector_type(8))) short bf16x8;  // 8 bf16 (MFMA K=32 A/B frag)
typedef __attribute__((ext_vector_type(4))) short bf16x4;  // 4 bf16 (MFMA K=16 A/B frag)
typedef __attribute__((ext_vector_type(4))) float f32x4;   // MFMA C/D frag

// __has_builtin for amdgcn builtins is false in the HOST pass; device-only check.
#if defined(__HIP_DEVICE_COMPILE__) && !__has_builtin(__builtin_amdgcn_mfma_f32_16x16x16bf16_1k)
#error "mfma_f32_16x16x16bf16_1k required on gfx950"
#endif
#define MFMA16(a, b, c) __builtin_amdgcn_mfma_f32_16x16x16bf16_1k(a, b, c, 0, 0, 0)
#define MFMA32(a, b, c) __builtin_amdgcn_mfma_f32_16x16x32_bf16(a, b, c, 0, 0, 0)

__device__ __forceinline__ unsigned short f2bf(float f) {
  union { float f; unsigned int u; } v; v.f = f;
  unsigned int u = v.u;
  u = u + 0x7fffu + ((u >> 16) & 1u);   // round-nearest-even
  return (unsigned short)(u >> 16);
}

// async global(16B/lane) -> LDS (wave-uniform dest base + lane*16)
__device__ __forceinline__ void gload16(const void* g, void* l) {
  __builtin_amdgcn_global_load_lds(
      (const __attribute__((address_space(1))) unsigned int*)g,
      (__attribute__((address_space(3))) unsigned int*)l, 16, 0, 0);
}

// ---------------------------------------------------------------------------
// k_prep: Wt[m][h][c] = W_m[c][h] as bf16.  grid=192 (m*64+h), block=256.
// ---------------------------------------------------------------------------
__global__ __launch_bounds__(256) void k_prep(const float* __restrict__ Wq,
                                              const float* __restrict__ Wk,
                                              const float* __restrict__ Wv,
                                              unsigned short* __restrict__ Wt) {
  const int m = blockIdx.x >> 6;
  const int h = blockIdx.x & 63;
  const float* W = (m == 0) ? Wq : (m == 1) ? Wk : Wv;
  const int tid = threadIdx.x;
  unsigned short* dst = Wt + ((size_t)(m * 64 + h)) * 1024;
#pragma unroll
  for (int j = 0; j < 4; ++j) {
    int c = j * 256 + tid;
    dst[c] = f2bf(W[(size_t)c * 64 + h]);
  }
}

// ---------------------------------------------------------------------------
// k_qkv: C[16384x192] = x * W (Q|K|V), bf16 MFMA.
// R12 theory: ALL prior variants (R8/R9/R11 ~38-39us) lacked EITHER wave
// concurrency (R9: 1 wave/SIMD, ~5700cyc/step vs ~2400 of pipe work = raw
// latency exposure) OR minimal W-restage (R10: 4 blk/CU doubled W traffic).
// This config has BOTH: 64-row x 192-col tiles, grid=256 (1 block/CU),
// block=1024 (16 waves = 4 waves/SIMD), per-CU-step W-fetch = 24KB minimum.
// Staging = R9's proven mechanics: dbuf 40KB stages, gload_lds both operands
// (zero staging registers), x as RAW FP32 (cvt at A-frag build, after the
// barrier, overlapped with MFMA), source granule-XOR swizzle, 1 barrier/step:
//   { stage(t+1) -> other buf; compute(t); barrier }
// Wave decomp: wid 0..15 -> (wm=wid>>2, wn=wid&3): 16 rows x 48 cols, acc[3].
// ---------------------------------------------------------------------------
__global__ __launch_bounds__(1024, 4) void k_qkv(const float* __restrict__ x,
                                                 const unsigned short* __restrict__ Wt,
                                                 unsigned short* __restrict__ Q,
                                                 unsigned short* __restrict__ K,
                                                 unsigned short* __restrict__ Vt) {
  // buf b at smem + b*40960: xf fp32 16KB | W bf16 24KB.  os[64][200] aliases buf0.
  __shared__ __align__(16) char smem[81920];

  const int tid = threadIdx.x;
  const int lane = tid & 63;
  const int wid = __builtin_amdgcn_readfirstlane(tid >> 6);  // 0..15
  const int wm = wid >> 2, wn = wid & 3;
  const int l15 = lane & 15, g = lane >> 4;
  const int r0 = blockIdx.x * 64;

  f32x4 acc[3];
#pragma unroll
  for (int j = 0; j < 3; ++j)
#pragma unroll
    for (int r = 0; r < 4; ++r) acc[j][r] = 0.f;

  // stage one K-step: 40 x 1KB chunks (x: 16 chunks of 4 rows x 64 fp32;
  // W: 24 chunks of 8 rows x 64 bf16), distributed c = wid, wid+16, wid+32.
  // Source pre-swizzled: phys granule p holds logical p^(row&7).
  auto stage = [&](int buf, int kt) {
    char* base = smem + buf * 40960;
    const int k0 = kt * 64;
    for (int c = wid; c < 40; c += 16) {
      if (c < 16) {                                  // x chunk (R9-verified map)
        const int row = c * 4 + (lane >> 4);
        const int lg = (lane & 15) ^ (row & 7);
        gload16(x + (size_t)(r0 + row) * 1024 + k0 + lg * 4, base + c * 1024);
      } else {                                       // W chunk (R9-verified map)
        const int cw = c - 16;
        const int row = cw * 8 + (lane >> 3);
        const int lg = (lane & 7) ^ (row & 7);
        gload16(Wt + (size_t)row * 1024 + k0 + lg * 8, base + 16384 + cw * 1024);
      }
    }
  };

  stage(0, 0);
  __syncthreads();

  const int myrow = wm * 16 + l15;                   // A-frag row (0..63)
  const int rs = myrow & 7;
  for (int kt = 0; kt < 16; ++kt) {
    const int cur = kt & 1;
    if (kt < 15) stage(cur ^ 1, kt + 1);             // flies under compute
    const char* base = smem + cur * 40960;
    const float* xf = (const float*)base;            // [64][64] fp32, swizzled
    const unsigned short* wf = (const unsigned short*)(base + 16384);
#pragma unroll
    for (int kf = 0; kf < 2; ++kf) {
      // A-frag: 8 fp32 -> bf16x8 (cvt overlapped with MFMA issue)
      f32x4 x0 = *(const f32x4*)&xf[myrow * 64 + (((kf * 8 + 2 * g) ^ rs) * 4)];
      f32x4 x1 = *(const f32x4*)&xf[myrow * 64 + (((kf * 8 + 2 * g + 1) ^ rs) * 4)];
      bf16x8 a;
      a[0] = (short)f2bf(x0[0]); a[1] = (short)f2bf(x0[1]);
      a[2] = (short)f2bf(x0[2]); a[3] = (short)f2bf(x0[3]);
      a[4] = (short)f2bf(x1[0]); a[5] = (short)f2bf(x1[1]);
      a[6] = (short)f2bf(x1[2]); a[7] = (short)f2bf(x1[3]);
#pragma unroll
      for (int nf = 0; nf < 3; ++nf) {
        const int row = wn * 48 + nf * 16 + l15;
        bf16x8 b = *(const bf16x8*)&wf[row * 64 + (((kf * 4 + g) ^ (row & 7)) * 8)];
        acc[nf] = MFMA32(a, b, acc[nf]);
      }
    }
    __syncthreads();   // drains stage(kt+1) vmcnt (free: loads << compute) +
                       // all waves done reading buf[cur]
  }

  // epilogue: acc -> os (bf16). D: col=l15, row=4g+r. os aliases buf0; last
  // compute read buf1 (kt=15) and buf0 readers passed the kt=14 barrier.
  unsigned short (*os)[200] = (unsigned short (*)[200])smem;
#pragma unroll
  for (int nf = 0; nf < 3; ++nf)
#pragma unroll
    for (int r = 0; r < 4; ++r)
      os[wm * 16 + 4 * g + r][wn * 48 + nf * 16 + l15] = f2bf(acc[nf][r]);
  __syncthreads();

  const int b = r0 >> 11;
  const int t0 = r0 & 2047;
  // Q, K: 64 rows x 8 uint4-chunks = 512 each; tid<512 -> Q, else K.
  {
    int u = tid & 511;
    int row = u >> 3, ch = u & 7;
    if (tid < 512)
      *(uint4*)(Q + (size_t)(r0 + row) * 64 + ch * 8) = *(const uint4*)&os[row][ch * 8];
    else
      *(uint4*)(K + (size_t)(r0 + row) * 64 + ch * 8) = *(const uint4*)&os[row][64 + ch * 8];
  }
  // Vt transpose: 64 h x 64 t; each thread 4 t-values (8B store).
  {
    int h = tid >> 4, tq = (tid & 15) * 4;
    unsigned short tmp[4];
#pragma unroll
    for (int r = 0; r < 4; ++r) tmp[r] = os[tq + r][128 + h];
    *(ushort4*)(Vt + ((size_t)b * 64 + h) * 2048 + t0 + tq) = *(const ushort4*)tmp;
  }
}

// ---------------------------------------------------------------------------
// k_attn_coop: block-cooperative flash attention. UNCHANGED from R7-R11
// (inferred ~11us: (256,3), XCD-bijective swizzle, gload_lds dbuf staging).
// ---------------------------------------------------------------------------
__global__ __launch_bounds__(256, 3) void k_attn_coop(const unsigned short* __restrict__ Q,
                                                      const unsigned short* __restrict__ K,
                                                      const unsigned short* __restrict__ Vt,
                                                      float* __restrict__ out,
                                                      float* __restrict__ po,
                                                      float* __restrict__ pml) {
  __shared__ __align__(16) unsigned short lds[2][8192];  // [buf][K 4096sh | V 4096sh]

  const int tid = threadIdx.x;
  const int lane = tid & 63;
  const int l15 = lane & 15, g = lane >> 4;
  const int wid = __builtin_amdgcn_readfirstlane(tid >> 6);

  // ---- task decode with XCD swizzle (1152 = 8 XCD x 144 tasks/batch) ----
  const int raw = blockIdx.x;
  const int bi = (raw & 7) * 144 + (raw >> 3);
  const int b = bi / 144;
  const int id = bi - b * 144;
  int gq = 0;
#pragma unroll
  for (int t = 1; t < 8; ++t)
    if (id >= 2 * t * (t + 1)) gq = t;
  const int rem = id - 2 * gq * (gq + 1);
  const int ql = rem / (gq + 1);
  const int s = rem - ql * (gq + 1);
  const int qt = 4 * gq + ql;          // 64-row q-tile 0..31
  const int qblk = qt * 64;
  const int klo = 256 * s;
  const int khi = min(klo + 256, qblk + 64);
  const int nt = (khi - klo + 63) >> 6;
  const int q0w = qblk + wid * 16;     // this wave's q rows

  const unsigned short* Qb = Q + (size_t)b * Tn * Hn;
  const unsigned short* Kb = K + (size_t)b * Tn * Hn;
  const unsigned short* Vb = Vt + (size_t)b * Hn * Tn;

  // Q as B-operand: lane l15 = q row, k = 8g+j
  bf16x8 bq0 = *(const bf16x8*)(Qb + (size_t)(q0w + l15) * 64 + g * 8);
  bf16x8 bq1 = *(const bf16x8*)(Qb + (size_t)(q0w + l15) * 64 + 32 + g * 8);

  f32x4 o[4];
#pragma unroll
  for (int hf = 0; hf < 4; ++hf)
#pragma unroll
    for (int r = 0; r < 4; ++r) o[hf][r] = 0.f;
  float m = -1e30f, lsum = 0.f;
  const float sc = 0.03125f * 1.44269504088896f;  // C^-0.5 * log2(e)

  // stage one 64-key tile: K[64key][64d] + V[64h][64key], swizzled granules.
  auto stage = [&](int buf, int k0) {
    unsigned short* tb = &lds[buf][0];
#pragma unroll
    for (int j = 0; j < 4; ++j) {
      const int p = wid * 256 + j * 64 + lane;
      const unsigned short* src;
      if (wid < 2) {                       // K: rows = keys
        const int row = p >> 3, c = p & 7;
        src = Kb + (size_t)(k0 + row) * 64 + ((c ^ (row & 7)) * 8);
      } else {                             // V: rows = h
        const int q = p - 512;
        const int h = q >> 3, c = q & 7;
        src = Vb + (size_t)h * Tn + k0 + ((c ^ (h & 7)) * 8);
      }
      gload16(src, tb + wid * 2048 + j * 512);
    }
  };

  stage(0, klo);
  __syncthreads();

  for (int t = 0; t < nt; ++t) {
    const int cur = t & 1;
    const int k0 = klo + t * 64;
    if (t + 1 < nt) stage(cur ^ 1, klo + (t + 1) * 64);

    const unsigned short* kt = &lds[cur][0];
    const unsigned short* vt = &lds[cur][4096];

    // S^T: lane l15 = q, reg (kc, 4g+r) = key
    f32x4 sacc[4];
#pragma unroll
    for (int kc = 0; kc < 4; ++kc) {
      const int row = kc * 16 + l15;
      const int sw = row & 7;
      bf16x8 ka = *(const bf16x8*)&kt[row * 64 + ((g ^ sw) * 8)];
      bf16x8 kb2 = *(const bf16x8*)&kt[row * 64 + (((4 + g) ^ sw) * 8)];
#pragma unroll
      for (int r = 0; r < 4; ++r) sacc[kc][r] = 0.f;
      sacc[kc] = MFMA32(ka, bq0, sacc[kc]);
      sacc[kc] = MFMA32(kb2, bq1, sacc[kc]);
    }
    // scale + causal mask (key <= q); boundary tiles only (wave-uniform)
    float sv[4][4];
    if (k0 + 63 > q0w) {
      const int q = q0w + l15;
#pragma unroll
      for (int kc = 0; kc < 4; ++kc)
#pragma unroll
        for (int r = 0; r < 4; ++r) {
          int key = k0 + kc * 16 + 4 * g + r;
          sv[kc][r] = (key <= q) ? sacc[kc][r] * sc : -1e30f;
        }
    } else {
#pragma unroll
      for (int kc = 0; kc < 4; ++kc)
#pragma unroll
        for (int r = 0; r < 4; ++r) sv[kc][r] = sacc[kc][r] * sc;
    }
    // defer-max: lane-local max suffices for the trigger test
    float pm = sv[0][0];
#pragma unroll
    for (int kc = 0; kc < 4; ++kc)
#pragma unroll
      for (int r = 0; r < 4; ++r) pm = fmaxf(pm, sv[kc][r]);
    if (__any(pm > m + 8.f)) {
      pm = fmaxf(pm, __shfl_xor(pm, 16));
      pm = fmaxf(pm, __shfl_xor(pm, 32));
      float mn = fmaxf(m, pm);
      float alpha = exp2f(m - mn);
      lsum *= alpha;
      float an[4];
#pragma unroll
      for (int r = 0; r < 4; ++r) an[r] = __shfl(alpha, 4 * g + r);
#pragma unroll
      for (int hf = 0; hf < 4; ++hf)
#pragma unroll
        for (int r = 0; r < 4; ++r) o[hf][r] *= an[r];
      m = mn;
    }
    float ts = 0.f;
#pragma unroll
    for (int kc = 0; kc < 4; ++kc)
#pragma unroll
      for (int r = 0; r < 4; ++r) { sv[kc][r] = exp2f(sv[kc][r] - m); ts += sv[kc][r]; }
    ts += __shfl_xor(ts, 16);
    ts += __shfl_xor(ts, 32);
    lsum += ts;
    // P in K=16 A-operand layout: lane l15 = q, k-local = 4g+r
    bf16x4 pa[4];
#pragma unroll
    for (int kc = 0; kc < 4; ++kc) {
      pa[kc][0] = (short)f2bf(sv[kc][0]); pa[kc][1] = (short)f2bf(sv[kc][1]);
      pa[kc][2] = (short)f2bf(sv[kc][2]); pa[kc][3] = (short)f2bf(sv[kc][3]);
    }
    // V frags from LDS: B-operand lane l15 = h col, k-local = 4g+r
    bf16x4 vf[4][4];
#pragma unroll
    for (int hf = 0; hf < 4; ++hf) {
      const int h = hf * 16 + l15, hs = h & 7;
#pragma unroll
      for (int kc = 0; kc < 4; ++kc) {
        const int gran = (kc * 2 + (g >> 1)) ^ hs;
        vf[hf][kc] = *(const bf16x4*)&vt[h * 64 + gran * 8 + (g & 1) * 4];
      }
    }
#pragma unroll
    for (int hf = 0; hf < 4; ++hf)
#pragma unroll
      for (int kc = 0; kc < 4; ++kc)
        o[hf] = MFMA16(pa[kc], vf[hf][kc], o[hf]);

    __syncthreads();   // drains stage vmcnt + all waves done reading buf
  }

  if (qt >= 4) {
    // packed partial: slot = task id - 4 within batch
    const int slot = b * 140 + id - 4;
    float* pob = po + (size_t)slot * 4096;
#pragma unroll
    for (int hf = 0; hf < 4; ++hf)
#pragma unroll
      for (int r = 0; r < 4; ++r)
        pob[(16 * wid + 4 * g + r) * 64 + hf * 16 + l15] = o[hf][r];
    if (lane < 16) {
      pml[(size_t)slot * 128 + 16 * wid + l15] = m;
      pml[(size_t)slot * 128 + 64 + 16 * wid + l15] = lsum;
    }
  } else {
    const float il = 1.f / lsum;
    float iln[4];
#pragma unroll
    for (int r = 0; r < 4; ++r) iln[r] = __shfl(il, 4 * g + r);
    float* ob = out + ((size_t)b * Tn + q0w) * 64;
#pragma unroll
    for (int hf = 0; hf < 4; ++hf)
#pragma unroll
      for (int r = 0; r < 4; ++r)
        ob[(size_t)(4 * g + r) * 64 + hf * 16 + l15] = o[hf][r] * iln[r];
  }
}

// ---------------------------------------------------------------------------
// k_comb: merge 2..8 segments per (b, qt 4..31). grid=(28,8), block=256.
// ---------------------------------------------------------------------------
__global__ __launch_bounds__(256) void k_comb(const float* __restrict__ po,
                                              const float* __restrict__ pml,
                                              float* __restrict__ out) {
  const int qt = 4 + blockIdx.x;
  const int b = blockIdx.y;
  const int gq = qt >> 2, ql = qt & 3;
  const int nseg = gq + 1;
  const int base = b * 140 + 2 * gq * (gq + 1) + ql * (gq + 1) - 4;
  const int r = threadIdx.x >> 2;
  const int cg = threadIdx.x & 3;

  float mv[8], lv[8], M = -1e30f;
#pragma unroll
  for (int s = 0; s < 8; ++s)
    if (s < nseg) {
      mv[s] = pml[(size_t)(base + s) * 128 + r];
      lv[s] = pml[(size_t)(base + s) * 128 + 64 + r];
      M = fmaxf(M, mv[s]);
    }
  float w[8], L = 0.f;
#pragma unroll
  for (int s = 0; s < 8; ++s)
    if (s < nseg) { w[s] = exp2f(mv[s] - M); L += w[s] * lv[s]; }

  float acc[16];
#pragma unroll
  for (int c = 0; c < 16; ++c) acc[c] = 0.f;
#pragma unroll
  for (int s = 0; s < 8; ++s)
    if (s < nseg) {
      const float* pb = po + (size_t)(base + s) * 4096 + r * 64 + cg * 16;
#pragma unroll
      for (int j = 0; j < 4; ++j) {
        float4 v = *(const float4*)(pb + 4 * j);
        acc[4 * j + 0] += w[s] * v.x; acc[4 * j + 1] += w[s] * v.y;
        acc[4 * j + 2] += w[s] * v.z; acc[4 * j + 3] += w[s] * v.w;
      }
    }
  const float invL = 1.f / L;
  float* ob = out + ((size_t)b * Tn + qt * 64 + r) * 64 + cg * 16;
#pragma unroll
  for (int j = 0; j < 4; ++j) {
    float4 v;
    v.x = acc[4 * j + 0] * invL; v.y = acc[4 * j + 1] * invL;
    v.z = acc[4 * j + 2] * invL; v.w = acc[4 * j + 3] * invL;
    *(float4*)(ob + 4 * j) = v;
  }
}

// ---------------------------------------------------------------------------
// k_attn_wave: per-wave fallback (full key range), tiny workspace only.
// ---------------------------------------------------------------------------
__global__ __launch_bounds__(256, 2) void k_attn_wave(const unsigned short* __restrict__ Q,
                                                      const unsigned short* __restrict__ K,
                                                      const unsigned short* __restrict__ Vt,
                                                      float* __restrict__ out) {
  const int tid = threadIdx.x;
  const int lane = tid & 63;
  const int l15 = lane & 15, g = lane >> 4;
  const int wid = tid >> 6;
  const int task = blockIdx.x * 4 + wid;
  const int b = task >> 7, qt = task & 127;
  const int q0 = qt * 16;
  const int nt = (q0 + 16 + 63) >> 6;

  const unsigned short* Qb = Q + (size_t)b * Tn * Hn;
  const unsigned short* Kb = K + (size_t)b * Tn * Hn;
  const unsigned short* Vb = Vt + (size_t)b * Hn * Tn;

  bf16x8 bq0 = *(const bf16x8*)(Qb + (size_t)(q0 + l15) * 64 + g * 8);
  bf16x8 bq1 = *(const bf16x8*)(Qb + (size_t)(q0 + l15) * 64 + 32 + g * 8);

  f32x4 o[4];
#pragma unroll
  for (int hf = 0; hf < 4; ++hf)
#pragma unroll
    for (int r = 0; r < 4; ++r) o[hf][r] = 0.f;
  float m = -1e30f, lsum = 0.f;
  const float sc = 0.03125f * 1.44269504088896f;

  for (int t = 0; t < nt; ++t) {
    const int k0 = t * 64;
    bf16x4 vf[4][4];
#pragma unroll
    for (int hf = 0; hf < 4; ++hf) {
      const unsigned short* vrow = Vb + (size_t)(hf * 16 + l15) * Tn + k0 + 4 * g;
#pragma unroll
      for (int kc = 0; kc < 4; ++kc) vf[hf][kc] = *(const bf16x4*)(vrow + kc * 16);
    }
    f32x4 sacc[4];
#pragma unroll
    for (int kc = 0; kc < 4; ++kc) {
      const unsigned short* kp = Kb + (size_t)(k0 + kc * 16 + l15) * 64 + g * 8;
      bf16x8 ka = *(const bf16x8*)kp;
      bf16x8 kb2 = *(const bf16x8*)(kp + 32);
#pragma unroll
      for (int r = 0; r < 4; ++r) sacc[kc][r] = 0.f;
      sacc[kc] = MFMA32(ka, bq0, sacc[kc]);
      sacc[kc] = MFMA32(kb2, bq1, sacc[kc]);
    }
    float sv[4][4];
    if (k0 + 63 > q0) {
      const int q = q0 + l15;
#pragma unroll
      for (int kc = 0; kc < 4; ++kc)
#pragma unroll
        for (int r = 0; r < 4; ++r) {
          int key = k0 + kc * 16 + 4 * g + r;
          sv[kc][r] = (key <= q) ? sacc[kc][r] * sc : -1e30f;
        }
    } else {
#pragma unroll
      for (int kc = 0; kc < 4; ++kc)
#pragma unroll
        for (int r = 0; r < 4; ++r) sv[kc][r] = sacc[kc][r] * sc;
    }
    float pm = sv[0][0];
#pragma unroll
    for (int kc = 0; kc < 4; ++kc)
#pragma unroll
      for (int r = 0; r < 4; ++r) pm = fmaxf(pm, sv[kc][r]);
    if (__any(pm > m + 8.f)) {
      pm = fmaxf(pm, __shfl_xor(pm, 16));
      pm = fmaxf(pm, __shfl_xor(pm, 32));
      float mn = fmaxf(m, pm);
      float alpha = exp2f(m - mn);
      lsum *= alpha;
      float an[4];
#pragma unroll
      for (int r = 0; r < 4; ++r) an[r] = __shfl(alpha, 4 * g + r);
#pragma unroll
      for (int hf = 0; hf < 4; ++hf)
#pragma unroll
        for (int r = 0; r < 4; ++r) o[hf][r] *= an[r];
      m = mn;
    }
    float ts = 0.f;
#pragma unroll
    for (int kc = 0; kc < 4; ++kc)
#pragma unroll
      for (int r = 0; r < 4; ++r) { sv[kc][r] = exp2f(sv[kc][r] - m); ts += sv[kc][r]; }
    ts += __shfl_xor(ts, 16);
    ts += __shfl_xor(ts, 32);
    lsum += ts;
    bf16x4 pa[4];
#pragma unroll
    for (int kc = 0; kc < 4; ++kc) {
      pa[kc][0] = (short)f2bf(sv[kc][0]); pa[kc][1] = (short)f2bf(sv[kc][1]);
      pa[kc][2] = (short)f2bf(sv[kc][2]); pa[kc][3] = (short)f2bf(sv[kc][3]);
    }
#pragma unroll
    for (int hf = 0; hf < 4; ++hf)
#pragma unroll
      for (int kc = 0; kc < 4; ++kc)
        o[hf] = MFMA16(pa[kc], vf[hf][kc], o[hf]);
  }
  const float il = 1.f / lsum;
  float iln[4];
#pragma unroll
  for (int r = 0; r < 4; ++r) iln[r] = __shfl(il, 4 * g + r);
  float* ob = out + ((size_t)b * Tn + q0) * 64;
#pragma unroll
  for (int hf = 0; hf < 4; ++hf)
#pragma unroll
    for (int r = 0; r < 4; ++r)
      ob[(size_t)(4 * g + r) * 64 + hf * 16 + l15] = o[hf][r] * iln[r];
}

// ---------------------------------------------------------------------------
extern "C" void kernel_launch(void* const* d_in, const int* in_sizes, int n_in,
                              void* d_out, int out_size, void* d_ws, size_t ws_size,
                              hipStream_t stream) {
  const float* x  = (const float*)d_in[0];
  const float* Wq = (const float*)d_in[1];
  const float* Wk = (const float*)d_in[2];
  const float* Wv = (const float*)d_in[3];
  float* out = (float*)d_out;

  // ws layout (bf16): Wt[3*64*1024] | Q | K | Vt  (each B*T*64), then fp32 partials
  unsigned short* Wt = (unsigned short*)d_ws;
  unsigned short* Qs = Wt + 3 * 64 * 1024;
  unsigned short* Ks = Qs + (size_t)Bn * Tn * Hn;
  unsigned short* Vt = Ks + (size_t)Bn * Tn * Hn;
  const size_t bf_bytes = (3 * 64 * 1024 + 3 * (size_t)Bn * Tn * Hn) * 2;
  float* po = (float*)((char*)d_ws + bf_bytes);

  const size_t nslots = (size_t)Bn * 140;   // packed partial slots
  float* pml = po + nslots * 4096;
  const size_t need = bf_bytes + nslots * (4096 + 128) * sizeof(float);  // ~25 MB

  hipLaunchKernelGGL(k_prep, dim3(192), dim3(256), 0, stream, Wq, Wk, Wv, Wt);
  hipLaunchKernelGGL(k_qkv, dim3(256), dim3(1024), 0, stream, x, Wt, Qs, Ks, Vt);
  if (ws_size >= need) {
    hipLaunchKernelGGL(k_attn_coop, dim3(1152), dim3(256), 0, stream, Qs, Ks, Vt, out, po, pml);
    hipLaunchKernelGGL(k_comb, dim3(28, 8), dim3(256), 0, stream, po, pml, out);
  } else {
    hipLaunchKernelGGL(k_attn_wave, dim3(256), dim3(256), 0, stream, Qs, Ks, Vt, out);
  }
}